// Round 11
// baseline (206.838 us; speedup 1.0000x reference)
//
#include <hip/hip_runtime.h>
#include <stdint.h>

// Dyna_Dec: out[b,d,l] = sum_c x[b,c,l] * w[l,c,d] + bias[l,d]
// B=128, C=32, L=4096, fp32 in/out.
//
// Evidence log:
//  - dur_us = hot kernels + ~92us fixed harness overhead (R5..R9).
//  - R8: runtime-indexed local arrays -> scratch. Literal-indexed unrolled
//    arrays (R9) -> WRITE exactly 64MiB. KEEP.
//  - R9 (all-coalesced scalar loads): 80us, VALU 20%, hbm 26%, occ 34%.
//    R6 gather was 88us -> pattern isn't the wall; CONCURRENCY is
//    (bytes-in-flight limited; occ tracks dur across R5..R9).
//  - R10: compile error — __builtin_nontemporal_load rejects HIP float4
//    (class type). Fix: native clang vector f32x4 = ext_vector_type(4).
//
// R11 = R10 design, f32x4 types: (1) float4-over-l -> 4x bytes/load-instr;
// (2) small tile (2b x 4d x 4l), ~110 VGPR, launch_bounds(256,4) -> 16
// waves/CU; (3) XCD swizzle (id&7): all blocks of an l-chunk on one XCD ->
// 256KB WT slice L2-resident; x nontemporal so it doesn't evict WT.

namespace {

constexpr int kC  = 32;
constexpr int kL  = 4096;
constexpr int kCD = kC * kC;  // 1024

using f32x4 = __attribute__((ext_vector_type(4))) float;

// ---------------- kernel 1: W transpose (R8/R9-proven) ----------------
// view W as A[L=4096][CD=1024]; write WT[CD][L].
__global__ __launch_bounds__(256)
void transpose_w(const float* __restrict__ w, float* __restrict__ wt) {
    __shared__ float tile[64][65];
    const int tx = threadIdx.x & 63;
    const int tg = threadIdx.x >> 6;          // 0..3
    const int cd0 = blockIdx.x * 64;          // gridDim.x = 16
    const int l0  = blockIdx.y * 64;          // gridDim.y = 64

#pragma unroll
    for (int k = 0; k < 16; ++k) {
        const int r = tg * 16 + k;            // l within tile
        tile[r][tx] = w[(size_t)(l0 + r) * kCD + cd0 + tx];
    }
    __syncthreads();
#pragma unroll
    for (int k = 0; k < 16; ++k) {
        const int r = tg * 16 + k;            // cd within tile
        wt[(size_t)(cd0 + r) * kL + l0 + tx] = tile[tx][r];
    }
}

// ---------------- kernel 2: compute, float4-over-l ----------------
// Block: 64 l x 8 b x 16 d. Thread: 4 l (f32x4) x 2 b x 4 d.
// t = [dg:2][bg:2][lg:4]; grid 2048 1D with XCD swizzle.
__global__ __launch_bounds__(256, 4)
void dyna_dec_v4(const float* __restrict__ x,
                 const float* __restrict__ wt,
                 const float* __restrict__ bias,
                 float* __restrict__ out) {
    const int t  = threadIdx.x;
    const int lg = t & 15;
    const int bg = (t >> 4) & 3;
    const int dg = t >> 6;

    const int id     = blockIdx.x;            // 0..2047
    const int xcd    = id & 7;
    const int s      = id >> 3;               // 0..255
    const int dblk   = s & 1;
    const int bblk   = (s >> 1) & 15;
    const int lchunk = (s >> 5) * 8 + xcd;    // 0..63; all blocks of an
                                              // l-chunk share id%8 -> same XCD
    const int l0 = lchunk * 64 + lg * 4;
    const int b0 = bblk * 8 + bg * 2;
    const int d0 = dblk * 16 + dg * 4;

    const float* xp = x  + (size_t)b0 * (kC * kL) + l0;  // + i*C*L + c*L
    const float* wp = wt + (size_t)d0 * kL + l0;         // + (c*32 + j)*L

    f32x4 acc[2][4];
#pragma unroll
    for (int i = 0; i < 2; ++i)
#pragma unroll
        for (int j = 0; j < 4; ++j)
            acc[i][j] = (f32x4)(0.0f);

    f32x4 xA[2], xB[2], wA[4], wB[4];

#define LOAD_X(dst, cc)                                                       \
    _Pragma("unroll") for (int i = 0; i < 2; ++i)                             \
        dst[i] = __builtin_nontemporal_load(reinterpret_cast<const f32x4*>(   \
            xp + (size_t)i * (kC * kL) + (size_t)(cc) * kL));
#define LOAD_W(dst, cc)                                                       \
    _Pragma("unroll") for (int j = 0; j < 4; ++j)                             \
        dst[j] = *reinterpret_cast<const f32x4*>(                             \
            wp + (size_t)((cc) * kC + j) * kL);
#define FMA_BLK(xa, wa)                                                       \
    _Pragma("unroll") for (int i = 0; i < 2; ++i)                             \
    _Pragma("unroll") for (int j = 0; j < 4; ++j)                             \
        acc[i][j] += xa[i] * wa[j];

    // preload A := c=0
    LOAD_X(xA, 0)
    LOAD_W(wA, 0)

    for (int c = 0; c < kC - 2; c += 2) {
        LOAD_X(xB, c + 1)
        LOAD_W(wB, c + 1)
        FMA_BLK(xA, wA)
        LOAD_X(xA, c + 2)
        LOAD_W(wA, c + 2)
        FMA_BLK(xB, wB)
    }
    // tail: A holds c=30
    LOAD_X(xB, kC - 1)
    LOAD_W(wB, kC - 1)
    FMA_BLK(xA, wA)
    FMA_BLK(xB, wB)

#undef LOAD_X
#undef LOAD_W
#undef FMA_BLK

    // bias[l0+u, d0..d0+3] for u=0..3 (one-time small gather)
    f32x4 brow[4];
#pragma unroll
    for (int u = 0; u < 4; ++u)
        brow[u] = *reinterpret_cast<const f32x4*>(bias + (size_t)(l0 + u) * kC + d0);

#pragma unroll
    for (int i = 0; i < 2; ++i) {
        float* op = out + (size_t)(b0 + i) * (kC * kL) + (size_t)d0 * kL + l0;
#pragma unroll
        for (int j = 0; j < 4; ++j) {
            f32x4 v = acc[i][j];
            v.x += brow[0][j];
            v.y += brow[1][j];
            v.z += brow[2][j];
            v.w += brow[3][j];
            *reinterpret_cast<f32x4*>(op + (size_t)j * kL) = v;  // plain store
        }
    }
}

// ---------------- fallback: R6-style gather (no workspace) ----------------
__global__ __launch_bounds__(256, 4)
void dyna_dec_gather(const float* __restrict__ x,
                     const float* __restrict__ w,
                     const float* __restrict__ bias,
                     float* __restrict__ out) {
    const int lt = threadIdx.x & 63;
    const int dg = threadIdx.x >> 6;
    const int l  = blockIdx.x * 64 + lt;
    const int b0 = blockIdx.y * 8;
    const int d0 = dg * 8;

    const float* wp = w + (size_t)l * kCD + d0;
    const float* xp = x + (size_t)b0 * (kC * kL) + l;

    float acc[8][8];
#pragma unroll
    for (int i = 0; i < 8; ++i)
#pragma unroll
        for (int j = 0; j < 8; ++j) acc[i][j] = 0.0f;

#pragma unroll 2
    for (int c = 0; c < kC; ++c) {
        const f32x4 w0 = *reinterpret_cast<const f32x4*>(wp + c * kC);
        const f32x4 w1 = *reinterpret_cast<const f32x4*>(wp + c * kC + 4);
        const float ws[8] = {w0.x, w0.y, w0.z, w0.w, w1.x, w1.y, w1.z, w1.w};
        float xr[8];
#pragma unroll
        for (int i = 0; i < 8; ++i)
            xr[i] = xp[(size_t)i * (kC * kL) + (size_t)c * kL];
#pragma unroll
        for (int i = 0; i < 8; ++i)
#pragma unroll
            for (int j = 0; j < 8; ++j)
                acc[i][j] += xr[i] * ws[j];
    }

    const f32x4 bv0 = *reinterpret_cast<const f32x4*>(bias + (size_t)l * kC + d0);
    const f32x4 bv1 = *reinterpret_cast<const f32x4*>(bias + (size_t)l * kC + d0 + 4);
    const float bb[8] = {bv0.x, bv0.y, bv0.z, bv0.w, bv1.x, bv1.y, bv1.z, bv1.w};
#pragma unroll
    for (int i = 0; i < 8; ++i) {
        float* op = out + ((size_t)(b0 + i) * kC + d0) * kL + l;
#pragma unroll
        for (int j = 0; j < 8; ++j)
            op[(size_t)j * kL] = acc[i][j] + bb[j];
    }
}

}  // namespace

extern "C" void kernel_launch(void* const* d_in, const int* in_sizes, int n_in,
                              void* d_out, int out_size, void* d_ws, size_t ws_size,
                              hipStream_t stream) {
    // inputs: 0=x (B,C,H,W) fp32, 1=px (unused), 2=weight (L*C, C) fp32,
    //         3=bias (L*C) fp32
    const float* x    = (const float*)d_in[0];
    const float* wgt  = (const float*)d_in[2];
    const float* bias = (const float*)d_in[3];
    float* out = (float*)d_out;

    const size_t wt_bytes = (size_t)kCD * kL * sizeof(float);  // 16 MiB
    if (ws_size >= wt_bytes) {
        float* wt = (float*)d_ws;
        hipLaunchKernelGGL(transpose_w, dim3(kCD / 64, kL / 64), dim3(256),
                           0, stream, wgt, wt);
        hipLaunchKernelGGL(dyna_dec_v4, dim3(2048), dim3(256),
                           0, stream, x, wt, bias, out);
    } else {
        hipLaunchKernelGGL(dyna_dec_gather, dim3(kL / 64, 16), dim3(256),
                           0, stream, x, wgt, bias, out);
    }
}